// Round 1
// baseline (6354.052 us; speedup 1.0000x reference)
//
#include <hip/hip_runtime.h>
#include <hip/hip_bf16.h>

// Problem constants
#define QN   2048
#define NN   100000
#define DD   1024
#define CC   1000
#define KK   50

// ---------------- init: running top-k state ----------------
__global__ void knn_init(float* __restrict__ ss, int* __restrict__ si) {
    int i = blockIdx.x * 256 + threadIdx.x;   // grid covers 2048*64
    ss[i] = -1e30f;
    si[i] = 0;
}

// ---------------- fp32 GEMM: scores[q][c] = dot(A[q], B[n0+c]) ----------------
#define TILE 128
#define BK   16

__global__ __launch_bounds__(256) void knn_gemm(
    const float* __restrict__ A,    // [QN][DD]
    const float* __restrict__ B,    // [NN][DD]
    float* __restrict__ out,        // [QN][stride] chunk scores
    int n0, int stride)
{
    __shared__ float As[BK][TILE + 4];
    __shared__ float Bs[BK][TILE + 4];

    const int tid = threadIdx.x;
    const int q0  = blockIdx.y * TILE;
    const int c0  = blockIdx.x * TILE;
    const int tx  = tid & 15;       // n-direction
    const int ty  = tid >> 4;       // q-direction

    float acc[8][8];
    #pragma unroll
    for (int i = 0; i < 8; ++i)
        #pragma unroll
        for (int j = 0; j < 8; ++j) acc[i][j] = 0.f;

    for (int k0 = 0; k0 < DD; k0 += BK) {
        // stage A-tile and B-tile (128 rows x 16 cols each), transposed into LDS
        #pragma unroll
        for (int i = 0; i < 2; ++i) {
            int f  = tid + 256 * i;        // 0..511
            int r  = f >> 2;               // 0..127
            int c4 = (f & 3) * 4;          // 0,4,8,12
            float4 va = *reinterpret_cast<const float4*>(
                &A[(size_t)(q0 + r) * DD + k0 + c4]);
            As[c4 + 0][r] = va.x; As[c4 + 1][r] = va.y;
            As[c4 + 2][r] = va.z; As[c4 + 3][r] = va.w;

            int brow = n0 + c0 + r;
            if (brow >= NN) brow = 0;      // clamp; garbage cols never read by merge
            float4 vb = *reinterpret_cast<const float4*>(
                &B[(size_t)brow * DD + k0 + c4]);
            Bs[c4 + 0][r] = vb.x; Bs[c4 + 1][r] = vb.y;
            Bs[c4 + 2][r] = vb.z; Bs[c4 + 3][r] = vb.w;
        }
        __syncthreads();

        #pragma unroll
        for (int k = 0; k < BK; ++k) {
            float a[8], b[8];
            *reinterpret_cast<float4*>(&a[0]) =
                *reinterpret_cast<const float4*>(&As[k][ty * 8]);
            *reinterpret_cast<float4*>(&a[4]) =
                *reinterpret_cast<const float4*>(&As[k][ty * 8 + 4]);
            *reinterpret_cast<float4*>(&b[0]) =
                *reinterpret_cast<const float4*>(&Bs[k][tx * 8]);
            *reinterpret_cast<float4*>(&b[4]) =
                *reinterpret_cast<const float4*>(&Bs[k][tx * 8 + 4]);
            #pragma unroll
            for (int i = 0; i < 8; ++i)
                #pragma unroll
                for (int j = 0; j < 8; ++j)
                    acc[i][j] += a[i] * b[j];
        }
        __syncthreads();
    }

    #pragma unroll
    for (int i = 0; i < 8; ++i) {
        int q = q0 + ty * 8 + i;
        float4 v0 = make_float4(acc[i][0], acc[i][1], acc[i][2], acc[i][3]);
        float4 v1 = make_float4(acc[i][4], acc[i][5], acc[i][6], acc[i][7]);
        float* dst = &out[(size_t)q * stride + c0 + tx * 8];
        *reinterpret_cast<float4*>(dst + 0) = v0;
        *reinterpret_cast<float4*>(dst + 4) = v1;
    }
}

// ---------------- merge: per-query top-50 of (chunk scores ∪ running top-k) ----------------
// Pool: 256 per-slice maxima + 64 old entries. 50 extraction rounds by wave 0.
__global__ __launch_bounds__(256) void knn_merge(
    float* __restrict__ sc,         // [QN][stride] chunk scores (marked during extraction)
    int stride, int cols, int n0,
    float* __restrict__ state_s, int* __restrict__ state_i)
{
    const int q = blockIdx.x;
    const int t = threadIdx.x;

    __shared__ float pool_s[320];
    __shared__ int   pool_i[320];
    __shared__ float win_s[KK];
    __shared__ int   win_i[KK];

    float* row = sc + (size_t)q * stride;

    // phase 1: per-thread slice max  (slice t = {t, t+256, ...} < cols)
    float m = -1e30f; int mi = -1;
    for (int j = t; j < cols; j += 256) {
        float v = row[j];
        if (v > m) { m = v; mi = j; }
    }
    pool_s[t] = m;
    pool_i[t] = (mi >= 0) ? (n0 + mi) : 0;
    if (t < 64) {                       // running top-k from previous chunks
        pool_s[256 + t] = state_s[q * 64 + t];
        pool_i[256 + t] = state_i[q * 64 + t];
    }
    __syncthreads();

    // phase 2: 50 extraction rounds
    for (int r = 0; r < KK; ++r) {
        float bs = -2e30f; int be = 0;
        if (t < 64) {
            bs = pool_s[t]; be = t;
            #pragma unroll
            for (int e = t + 64; e < 320; e += 64) {
                float v = pool_s[e];
                if (v > bs || (v == bs && e < be)) { bs = v; be = e; }
            }
            // butterfly: all 64 lanes converge on same (bs,be)
            #pragma unroll
            for (int msk = 32; msk; msk >>= 1) {
                float os = __shfl_xor(bs, msk);
                int   oe = __shfl_xor(be, msk);
                if (os > bs || (os == bs && oe < be)) { bs = os; be = oe; }
            }
            if (t == 0) {
                win_s[r] = bs;
                win_i[r] = pool_i[be];
                if (be < 256) row[pool_i[be] - n0] = -1e30f;   // mark taken
            }
        }
        __syncthreads();   // mark visible before rescan; win/pool ordering

        if (t < 64) {
            if (be < 256) {
                // rescan slice `be` cooperatively (64 lanes)
                float nm = -1e30f; int nmi = -1;
                for (int j = be + 256 * t; j < cols; j += 256 * 64) {
                    float v = row[j];
                    if (v > nm || (v == nm && j < nmi)) { nm = v; nmi = j; }
                }
                #pragma unroll
                for (int msk = 32; msk; msk >>= 1) {
                    float om  = __shfl_xor(nm, msk);
                    int   omi = __shfl_xor(nmi, msk);
                    if (om > nm || (om == nm && omi >= 0 && (nmi < 0 || omi < nmi))) {
                        nm = om; nmi = omi;
                    }
                }
                if (t == 0) {
                    pool_s[be] = nm;
                    pool_i[be] = (nmi >= 0) ? (n0 + nmi) : 0;
                }
            } else if (t == 0) {
                pool_s[be] = -2e30f;    // old entry consumed
            }
        }
        __syncthreads();
    }

    // write back running top-k
    if (t < 64) {
        if (t < KK) {
            state_s[q * 64 + t] = win_s[t];
            state_i[q * 64 + t] = win_i[t];
        } else {
            state_s[q * 64 + t] = -1e30f;
            state_i[q * 64 + t] = 0;
        }
    }
}

// ---------------- vote: class histogram, normalize, write preds + targets ----------------
__global__ __launch_bounds__(256) void knn_vote(
    const float* __restrict__ state_s, const int* __restrict__ state_i,
    const int* __restrict__ labels, const int* __restrict__ targets,
    float* __restrict__ out)
{
    const int q = blockIdx.x;
    const int t = threadIdx.x;
    __shared__ float hist[CC];
    __shared__ float ssum;

    for (int c = t; c < CC; c += 256) hist[c] = 0.f;
    if (t == 0) ssum = 0.f;
    __syncthreads();

    if (t < KK) {
        float s = state_s[q * 64 + t];
        int   idx = state_i[q * 64 + t];
        if (s > -1e29f) {
            int lab = labels[idx];
            atomicAdd(&hist[lab], s);
            atomicAdd(&ssum, s);
        }
    }
    __syncthreads();

    float denom = ssum;
    if (denom == 0.f) denom = 1.f;
    float inv = 1.f / denom;
    for (int c = t; c < CC; c += 256)
        out[(size_t)q * CC + c] = hist[c] * inv;
    if (t == 0)
        out[(size_t)QN * CC + q] = (float)targets[q];
}

// ---------------- host launch ----------------
extern "C" void kernel_launch(void* const* d_in, const int* in_sizes, int n_in,
                              void* d_out, int out_size, void* d_ws, size_t ws_size,
                              hipStream_t stream) {
    const float* samples = (const float*)d_in[0];   // [QN][DD]
    const int*   targets = (const int*)d_in[1];     // [QN]
    const float* train   = (const float*)d_in[2];   // [NN][DD]
    const int*   labels  = (const int*)d_in[3];     // [NN]
    float* out = (float*)d_out;

    float* state_s = (float*)d_ws;                                   // 2048*64 f32
    int*   state_i = (int*)((char*)d_ws + 512 * 1024);               // 2048*64 i32
    float* scores  = (float*)((char*)d_ws + 2 * 1024 * 1024);

    // chunk the N dimension to fit workspace
    long long avail = (long long)ws_size - 2 * 1024 * 1024;
    long long chunk = (avail / ((long long)QN * 4)) & ~127LL;
    const long long NPAD = ((NN + 127) / 128) * 128;                 // 100096
    if (chunk > NPAD) chunk = NPAD;
    if (chunk < 128)  chunk = 128;                                   // minimal fallback

    knn_init<<<(QN * 64) / 256, 256, 0, stream>>>(state_s, state_i);

    for (int n0 = 0; n0 < NN; n0 += (int)chunk) {
        int rem        = NN - n0;
        int cols_valid = rem < (int)chunk ? rem : (int)chunk;
        int cols_pad   = (cols_valid + 127) & ~127;
        dim3 grid(cols_pad / TILE, QN / TILE);
        knn_gemm<<<grid, 256, 0, stream>>>(samples, train, scores, n0, (int)chunk);
        knn_merge<<<QN, 256, 0, stream>>>(scores, (int)chunk, cols_valid, n0,
                                          state_s, state_i);
    }

    knn_vote<<<QN, 256, 0, stream>>>(state_s, state_i, labels, targets, out);
}

// Round 2
// 3152.567 us; speedup vs baseline: 2.0155x; 2.0155x over previous
//
#include <hip/hip_runtime.h>
#include <hip/hip_bf16.h>

// Problem constants
#define QN    2048
#define NN    100000
#define DD    1024
#define CC    1000
#define KK    50
#define BROWS 100096   // NN padded to multiple of 128

typedef short bf16x8 __attribute__((ext_vector_type(8)));
typedef float f32x4  __attribute__((ext_vector_type(4)));

__device__ __forceinline__ unsigned short f2bf_rn(float x) {
    unsigned u = __float_as_uint(x);
    u += 0x7fff + ((u >> 16) & 1);          // round-to-nearest-even
    return (unsigned short)(u >> 16);
}
__device__ __forceinline__ float bf2f(unsigned short h) {
    return __uint_as_float(((unsigned)h) << 16);
}

// ---------------- init: running top-k state ----------------
__global__ void knn_init(float* __restrict__ ss, int* __restrict__ si) {
    int i = blockIdx.x * 256 + threadIdx.x;   // grid covers 2048*64
    ss[i] = -1e30f;
    si[i] = 0;
}

// ---------------- convert: fp32 -> bf16 hi + bf16 lo(residual) ----------------
// one block per (padded) row; 256 threads x 4 floats = 1024 = DD
__global__ __launch_bounds__(256) void knn_convert(
    const float* __restrict__ src, short* __restrict__ hi, short* __restrict__ lo,
    int rows_valid)
{
    const int n  = blockIdx.x;
    const int k4 = threadIdx.x << 2;
    float4 v = make_float4(0.f, 0.f, 0.f, 0.f);
    if (n < rows_valid)
        v = *reinterpret_cast<const float4*>(&src[(size_t)n * DD + k4]);

    unsigned short h0 = f2bf_rn(v.x), h1 = f2bf_rn(v.y);
    unsigned short h2 = f2bf_rn(v.z), h3 = f2bf_rn(v.w);
    short4 hv = make_short4((short)h0, (short)h1, (short)h2, (short)h3);
    short4 lv = make_short4((short)f2bf_rn(v.x - bf2f(h0)),
                            (short)f2bf_rn(v.y - bf2f(h1)),
                            (short)f2bf_rn(v.z - bf2f(h2)),
                            (short)f2bf_rn(v.w - bf2f(h3)));
    *reinterpret_cast<short4*>(&hi[(size_t)n * DD + k4]) = hv;
    *reinterpret_cast<short4*>(&lo[(size_t)n * DD + k4]) = lv;
}

// ---------------- MFMA GEMM: scores = Ahi·Bhi^T + Alo·Bhi^T + Ahi·Blo^T ----------------
// 128x128 tile, BK=32, 4 waves (each 64x64 via 4x4 of 16x16x32), global_load_lds width=16
#define GL(gptr, ldsptr) __builtin_amdgcn_global_load_lds(                    \
    (const __attribute__((address_space(1))) void*)(gptr),                    \
    (__attribute__((address_space(3))) void*)(ldsptr), 16, 0, 0)

__global__ __launch_bounds__(256) void knn_gemm(
    const short* __restrict__ Ahi, const short* __restrict__ Alo,
    const short* __restrict__ Bhi, const short* __restrict__ Blo,
    float* __restrict__ out, int n0, int stride)
{
    __shared__ short As_hi[128][32];
    __shared__ short As_lo[128][32];
    __shared__ short Bs_hi[128][32];
    __shared__ short Bs_lo[128][32];

    const int tid  = threadIdx.x;
    const int lane = tid & 63;
    const int w    = tid >> 6;
    const int wm   = (w >> 1) * 64;      // wave's M offset in tile
    const int wn   = (w & 1) * 64;       // wave's N offset in tile
    const int q0   = blockIdx.y * 128;
    const int c0   = blockIdx.x * 128;

    const int srow = w * 32 + (lane >> 2);   // staging row (t=0), +16 for t=1
    const int kb   = (lane & 3) * 16;        // byte offset within 64B k-slice
    const int fr   = lane & 15;              // fragment row (m or n)
    const int fq   = lane >> 4;              // fragment quad

    f32x4 acc[4][4];
    #pragma unroll
    for (int i = 0; i < 4; ++i)
        #pragma unroll
        for (int j = 0; j < 4; ++j)
            acc[i][j] = (f32x4){0.f, 0.f, 0.f, 0.f};

    const size_t arow = (size_t)(q0 + srow);
    const size_t brow = (size_t)(n0 + c0 + srow);
    char* lds_ah = (char*)As_hi + (w * 32) * 64;   // wave-uniform LDS bases
    char* lds_al = (char*)As_lo + (w * 32) * 64;
    char* lds_bh = (char*)Bs_hi + (w * 32) * 64;
    char* lds_bl = (char*)Bs_lo + (w * 32) * 64;

    for (int k0 = 0; k0 < DD; k0 += 32) {
        const size_t ab = (arow * DD + k0) * 2 + kb;     // byte offsets
        const size_t bb = (brow * DD + k0) * 2 + kb;
        const size_t rstep = (size_t)16 * DD * 2;        // +16 rows

        GL((const char*)Ahi + ab,         lds_ah);
        GL((const char*)Ahi + ab + rstep, lds_ah + 16 * 64);
        GL((const char*)Alo + ab,         lds_al);
        GL((const char*)Alo + ab + rstep, lds_al + 16 * 64);
        GL((const char*)Bhi + bb,         lds_bh);
        GL((const char*)Bhi + bb + rstep, lds_bh + 16 * 64);
        GL((const char*)Blo + bb,         lds_bl);
        GL((const char*)Blo + bb + rstep, lds_bl + 16 * 64);
        __syncthreads();   // drains vmcnt(0) before barrier

        bf16x8 ah[4], al[4], bh[4], bl[4];
        #pragma unroll
        for (int i = 0; i < 4; ++i) {
            ah[i] = *reinterpret_cast<const bf16x8*>(&As_hi[wm + i * 16 + fr][fq * 8]);
            al[i] = *reinterpret_cast<const bf16x8*>(&As_lo[wm + i * 16 + fr][fq * 8]);
            bh[i] = *reinterpret_cast<const bf16x8*>(&Bs_hi[wn + i * 16 + fr][fq * 8]);
            bl[i] = *reinterpret_cast<const bf16x8*>(&Bs_lo[wn + i * 16 + fr][fq * 8]);
        }

        #pragma unroll
        for (int i = 0; i < 4; ++i)
            #pragma unroll
            for (int j = 0; j < 4; ++j) {
                acc[i][j] = __builtin_amdgcn_mfma_f32_16x16x32_bf16(ah[i], bh[j], acc[i][j], 0, 0, 0);
                acc[i][j] = __builtin_amdgcn_mfma_f32_16x16x32_bf16(al[i], bh[j], acc[i][j], 0, 0, 0);
                acc[i][j] = __builtin_amdgcn_mfma_f32_16x16x32_bf16(ah[i], bl[j], acc[i][j], 0, 0, 0);
            }
        __syncthreads();
    }

    // epilogue: D layout col=lane&15, row=(lane>>4)*4+reg  [m89-verified]
    #pragma unroll
    for (int i = 0; i < 4; ++i) {
        const int qrow = q0 + wm + i * 16 + fq * 4;
        #pragma unroll
        for (int j = 0; j < 4; ++j) {
            const int col = c0 + wn + j * 16 + fr;
            float* dst = &out[(size_t)qrow * stride + col];
            dst[0 * (size_t)stride] = acc[i][j][0];
            dst[1 * (size_t)stride] = acc[i][j][1];
            dst[2 * (size_t)stride] = acc[i][j][2];
            dst[3 * (size_t)stride] = acc[i][j][3];
        }
    }
}

// ---------------- merge: per-query top-50 of (chunk scores ∪ running top-k) ----------------
__global__ __launch_bounds__(256) void knn_merge(
    float* __restrict__ sc,         // [QN][stride] chunk scores (marked during extraction)
    int stride, int cols, int n0,
    float* __restrict__ state_s, int* __restrict__ state_i)
{
    const int q = blockIdx.x;
    const int t = threadIdx.x;

    __shared__ float pool_s[320];
    __shared__ int   pool_i[320];
    __shared__ float win_s[KK];
    __shared__ int   win_i[KK];

    float* row = sc + (size_t)q * stride;

    float m = -1e30f; int mi = -1;
    for (int j = t; j < cols; j += 256) {
        float v = row[j];
        if (v > m) { m = v; mi = j; }
    }
    pool_s[t] = m;
    pool_i[t] = (mi >= 0) ? (n0 + mi) : 0;
    if (t < 64) {
        pool_s[256 + t] = state_s[q * 64 + t];
        pool_i[256 + t] = state_i[q * 64 + t];
    }
    __syncthreads();

    for (int r = 0; r < KK; ++r) {
        float bs = -2e30f; int be = 0;
        if (t < 64) {
            bs = pool_s[t]; be = t;
            #pragma unroll
            for (int e = t + 64; e < 320; e += 64) {
                float v = pool_s[e];
                if (v > bs || (v == bs && e < be)) { bs = v; be = e; }
            }
            #pragma unroll
            for (int msk = 32; msk; msk >>= 1) {
                float os = __shfl_xor(bs, msk);
                int   oe = __shfl_xor(be, msk);
                if (os > bs || (os == bs && oe < be)) { bs = os; be = oe; }
            }
            if (t == 0) {
                win_s[r] = bs;
                win_i[r] = pool_i[be];
                if (be < 256) row[pool_i[be] - n0] = -1e30f;
            }
        }
        __syncthreads();

        if (t < 64) {
            if (be < 256) {
                float nm = -1e30f; int nmi = -1;
                for (int j = be + 256 * t; j < cols; j += 256 * 64) {
                    float v = row[j];
                    if (v > nm || (v == nm && j < nmi)) { nm = v; nmi = j; }
                }
                #pragma unroll
                for (int msk = 32; msk; msk >>= 1) {
                    float om  = __shfl_xor(nm, msk);
                    int   omi = __shfl_xor(nmi, msk);
                    if (om > nm || (om == nm && omi >= 0 && (nmi < 0 || omi < nmi))) {
                        nm = om; nmi = omi;
                    }
                }
                if (t == 0) {
                    pool_s[be] = nm;
                    pool_i[be] = (nmi >= 0) ? (n0 + nmi) : 0;
                }
            } else if (t == 0) {
                pool_s[be] = -2e30f;
            }
        }
        __syncthreads();
    }

    if (t < 64) {
        if (t < KK) {
            state_s[q * 64 + t] = win_s[t];
            state_i[q * 64 + t] = win_i[t];
        } else {
            state_s[q * 64 + t] = -1e30f;
            state_i[q * 64 + t] = 0;
        }
    }
}

// ---------------- vote: class histogram, normalize, write preds + targets ----------------
__global__ __launch_bounds__(256) void knn_vote(
    const float* __restrict__ state_s, const int* __restrict__ state_i,
    const int* __restrict__ labels, const int* __restrict__ targets,
    float* __restrict__ out)
{
    const int q = blockIdx.x;
    const int t = threadIdx.x;
    __shared__ float hist[CC];
    __shared__ float ssum;

    for (int c = t; c < CC; c += 256) hist[c] = 0.f;
    if (t == 0) ssum = 0.f;
    __syncthreads();

    if (t < KK) {
        float s = state_s[q * 64 + t];
        int   idx = state_i[q * 64 + t];
        if (s > -1e29f) {
            int lab = labels[idx];
            atomicAdd(&hist[lab], s);
            atomicAdd(&ssum, s);
        }
    }
    __syncthreads();

    float denom = ssum;
    if (denom == 0.f) denom = 1.f;
    float inv = 1.f / denom;
    for (int c = t; c < CC; c += 256)
        out[(size_t)q * CC + c] = hist[c] * inv;
    if (t == 0)
        out[(size_t)QN * CC + q] = (float)targets[q];
}

// ---------------- host launch ----------------
extern "C" void kernel_launch(void* const* d_in, const int* in_sizes, int n_in,
                              void* d_out, int out_size, void* d_ws, size_t ws_size,
                              hipStream_t stream) {
    const float* samples = (const float*)d_in[0];   // [QN][DD]
    const int*   targets = (const int*)d_in[1];     // [QN]
    const float* train   = (const float*)d_in[2];   // [NN][DD]
    const int*   labels  = (const int*)d_in[3];     // [NN]
    float* out = (float*)d_out;

    char* ws = (char*)d_ws;
    float* state_s = (float*)ws;                         // 2048*64 f32 = 512KB
    int*   state_i = (int*)(ws + (512 << 10));           // 512KB
    short* Ahi = (short*)(ws + (2 << 20));               // 4MB
    short* Alo = Ahi + (size_t)QN * DD;                  // 4MB
    short* Bhi = (short*)(ws + (12 << 20));              // ~195.5MB
    short* Blo = Bhi + (size_t)BROWS * DD;               // ~195.5MB
    size_t scores_off = (size_t)(12 << 20) + 2 * (size_t)BROWS * DD * 2;
    float* scores = (float*)(ws + scores_off);

    long long avail = (long long)ws_size - (long long)scores_off;
    long long chunk = (avail / ((long long)QN * 4)) & ~127LL;
    if (chunk > BROWS) chunk = BROWS;
    if (chunk < 128)   chunk = 128;

    knn_init<<<(QN * 64) / 256, 256, 0, stream>>>(state_s, state_i);
    knn_convert<<<QN,    256, 0, stream>>>(samples, Ahi, Alo, QN);
    knn_convert<<<BROWS, 256, 0, stream>>>(train,   Bhi, Blo, NN);

    for (int n0 = 0; n0 < NN; n0 += (int)chunk) {
        int rem        = NN - n0;
        int cols_valid = rem < (int)chunk ? rem : (int)chunk;
        int cols_pad   = (cols_valid + 127) & ~127;
        dim3 grid(cols_pad / 128, QN / 128);
        knn_gemm<<<grid, 256, 0, stream>>>(Ahi, Alo, Bhi, Blo, scores, n0, (int)chunk);
        knn_merge<<<QN, 256, 0, stream>>>(scores, (int)chunk, cols_valid, n0,
                                          state_s, state_i);
    }

    knn_vote<<<QN, 256, 0, stream>>>(state_s, state_i, labels, targets, out);
}

// Round 3
// 2807.252 us; speedup vs baseline: 2.2634x; 1.1230x over previous
//
#include <hip/hip_runtime.h>
#include <hip/hip_bf16.h>

// Problem constants
#define QN    2048
#define NN    100000
#define DD    1024
#define CC    1000
#define KK    50
#define BROWS 100096   // NN padded to multiple of 128
#define CHUNK 12544    // 98 * 128; scores chunk = 2048*12544*4 = 103 MB < LLC
#define NBMAX 98       // CHUNK/128

typedef short bf16x8 __attribute__((ext_vector_type(8)));
typedef float f32x4  __attribute__((ext_vector_type(4)));

__device__ __forceinline__ unsigned short f2bf_rn(float x) {
    unsigned u = __float_as_uint(x);
    u += 0x7fff + ((u >> 16) & 1);          // round-to-nearest-even
    return (unsigned short)(u >> 16);
}
__device__ __forceinline__ float bf2f(unsigned short h) {
    return __uint_as_float(((unsigned)h) << 16);
}

// ---------------- init: running top-k state ----------------
__global__ void knn_init(float* __restrict__ ss, int* __restrict__ si) {
    int i = blockIdx.x * 256 + threadIdx.x;   // grid covers 2048*64
    ss[i] = -1e30f;
    si[i] = 0;
}

// ---------------- convert: fp32 -> bf16 hi + bf16 lo(residual) ----------------
__global__ __launch_bounds__(256) void knn_convert(
    const float* __restrict__ src, short* __restrict__ hi, short* __restrict__ lo,
    int rows_valid)
{
    const int n  = blockIdx.x;
    const int k4 = threadIdx.x << 2;
    float4 v = make_float4(0.f, 0.f, 0.f, 0.f);
    if (n < rows_valid)
        v = *reinterpret_cast<const float4*>(&src[(size_t)n * DD + k4]);

    unsigned short h0 = f2bf_rn(v.x), h1 = f2bf_rn(v.y);
    unsigned short h2 = f2bf_rn(v.z), h3 = f2bf_rn(v.w);
    short4 hv = make_short4((short)h0, (short)h1, (short)h2, (short)h3);
    short4 lv = make_short4((short)f2bf_rn(v.x - bf2f(h0)),
                            (short)f2bf_rn(v.y - bf2f(h1)),
                            (short)f2bf_rn(v.z - bf2f(h2)),
                            (short)f2bf_rn(v.w - bf2f(h3)));
    *reinterpret_cast<short4*>(&hi[(size_t)n * DD + k4]) = hv;
    *reinterpret_cast<short4*>(&lo[(size_t)n * DD + k4]) = lv;
}

// ---------------- MFMA GEMM: scores = Ahi·Bhi^T + Alo·Bhi^T + Ahi·Blo^T ----------------
// 128x128 tile, BK=32, 4 waves (each 64x64 via 4x4 of 16x16x32), global_load_lds w=16.
// grid = (16 q-blocks [x, fastest], nblk col-blocks [y]) so 16 consecutive
// workgroups share one B tile (L2/LLC reuse).
#define GL(gptr, ldsptr) __builtin_amdgcn_global_load_lds(                    \
    (const __attribute__((address_space(1))) void*)(gptr),                    \
    (__attribute__((address_space(3))) void*)(ldsptr), 16, 0, 0)

__global__ __launch_bounds__(256) void knn_gemm(
    const short* __restrict__ Ahi, const short* __restrict__ Alo,
    const short* __restrict__ Bhi, const short* __restrict__ Blo,
    float* __restrict__ out, int n0, int cols_valid)
{
    __shared__ short As_hi[128][32];
    __shared__ short As_lo[128][32];
    __shared__ short Bs_hi[128][32];
    __shared__ short Bs_lo[128][32];

    const int tid  = threadIdx.x;
    const int lane = tid & 63;
    const int w    = tid >> 6;
    const int wm   = (w >> 1) * 64;      // wave's M offset in tile
    const int wn   = (w & 1) * 64;       // wave's N offset in tile
    const int q0   = blockIdx.x * 128;   // q on x: adjacent blocks share B tile
    const int c0   = blockIdx.y * 128;

    const int srow = w * 32 + (lane >> 2);   // staging row (t=0), +16 for t=1
    const int kb   = (lane & 3) * 16;        // byte offset within 64B k-slice
    const int fr   = lane & 15;              // fragment row (m or n)
    const int fq   = lane >> 4;              // fragment quad

    f32x4 acc[4][4];
    #pragma unroll
    for (int i = 0; i < 4; ++i)
        #pragma unroll
        for (int j = 0; j < 4; ++j)
            acc[i][j] = (f32x4){0.f, 0.f, 0.f, 0.f};

    const size_t arow = (size_t)(q0 + srow);
    const size_t brow = (size_t)(n0 + c0 + srow);
    char* lds_ah = (char*)As_hi + (w * 32) * 64;   // wave-uniform LDS bases
    char* lds_al = (char*)As_lo + (w * 32) * 64;
    char* lds_bh = (char*)Bs_hi + (w * 32) * 64;
    char* lds_bl = (char*)Bs_lo + (w * 32) * 64;

    for (int k0 = 0; k0 < DD; k0 += 32) {
        const size_t ab = (arow * DD + k0) * 2 + kb;     // byte offsets
        const size_t bb = (brow * DD + k0) * 2 + kb;
        const size_t rstep = (size_t)16 * DD * 2;        // +16 rows

        GL((const char*)Ahi + ab,         lds_ah);
        GL((const char*)Ahi + ab + rstep, lds_ah + 16 * 64);
        GL((const char*)Alo + ab,         lds_al);
        GL((const char*)Alo + ab + rstep, lds_al + 16 * 64);
        GL((const char*)Bhi + bb,         lds_bh);
        GL((const char*)Bhi + bb + rstep, lds_bh + 16 * 64);
        GL((const char*)Blo + bb,         lds_bl);
        GL((const char*)Blo + bb + rstep, lds_bl + 16 * 64);
        __syncthreads();   // drains vmcnt(0) before barrier

        bf16x8 ah[4], al[4], bh[4], bl[4];
        #pragma unroll
        for (int i = 0; i < 4; ++i) {
            ah[i] = *reinterpret_cast<const bf16x8*>(&As_hi[wm + i * 16 + fr][fq * 8]);
            al[i] = *reinterpret_cast<const bf16x8*>(&As_lo[wm + i * 16 + fr][fq * 8]);
            bh[i] = *reinterpret_cast<const bf16x8*>(&Bs_hi[wn + i * 16 + fr][fq * 8]);
            bl[i] = *reinterpret_cast<const bf16x8*>(&Bs_lo[wn + i * 16 + fr][fq * 8]);
        }

        #pragma unroll
        for (int i = 0; i < 4; ++i)
            #pragma unroll
            for (int j = 0; j < 4; ++j) {
                acc[i][j] = __builtin_amdgcn_mfma_f32_16x16x32_bf16(ah[i], bh[j], acc[i][j], 0, 0, 0);
                acc[i][j] = __builtin_amdgcn_mfma_f32_16x16x32_bf16(al[i], bh[j], acc[i][j], 0, 0, 0);
                acc[i][j] = __builtin_amdgcn_mfma_f32_16x16x32_bf16(ah[i], bl[j], acc[i][j], 0, 0, 0);
            }
        __syncthreads();
    }

    // epilogue: D layout col=lane&15, row=(lane>>4)*4+reg  [m89-verified]
    // mask padded columns to -1e30 so the select/merge stages need no bounds logic
    #pragma unroll
    for (int i = 0; i < 4; ++i) {
        const int qrow = q0 + wm + i * 16 + fq * 4;
        #pragma unroll
        for (int j = 0; j < 4; ++j) {
            const int col = c0 + wn + j * 16 + fr;
            const bool ok = (col < cols_valid);
            float* dst = &out[(size_t)qrow * CHUNK + col];
            dst[0 * (size_t)CHUNK] = ok ? acc[i][j][0] : -1e30f;
            dst[1 * (size_t)CHUNK] = ok ? acc[i][j][1] : -1e30f;
            dst[2 * (size_t)CHUNK] = ok ? acc[i][j][2] : -1e30f;
            dst[3 * (size_t)CHUNK] = ok ? acc[i][j][3] : -1e30f;
        }
    }
}

// ---------------- select: per-(q, 128-col-block) argmax (LLC-resident reads) ----------------
// one wave per (q, blk) pair; 4 waves per workgroup
__global__ __launch_bounds__(256) void knn_select(
    const float* __restrict__ sc, float* __restrict__ bm_s, int* __restrict__ bm_i,
    int nblk)
{
    const int pid  = blockIdx.x * 4 + (threadIdx.x >> 6);
    const int lane = threadIdx.x & 63;
    if (pid >= QN * nblk) return;
    const int q = pid / nblk;
    const int b = pid - q * nblk;

    const float* row = sc + (size_t)q * CHUNK + b * 128;
    float v0 = row[lane];
    float v1 = row[lane + 64];
    int   i0 = b * 128 + lane;
    int   i1 = b * 128 + lane + 64;
    if (v1 > v0) { v0 = v1; i0 = i1; }
    #pragma unroll
    for (int msk = 32; msk; msk >>= 1) {
        float ov = __shfl_xor(v0, msk);
        int   oi = __shfl_xor(i0, msk);
        if (ov > v0) { v0 = ov; i0 = oi; }
    }
    if (lane == 0) {
        bm_s[(size_t)q * nblk + b] = v0;
        bm_i[(size_t)q * nblk + b] = i0;        // chunk-local col
    }
}

// ---------------- merge: per-query top-50 of (block maxima ∪ running top-k) ----------------
// pool = nblk (<=98) slice maxima + 64 state entries; 50 extraction rounds,
// each with a 128-element LLC-hit rescan of the winning slice.
__global__ __launch_bounds__(256) void knn_merge(
    float* __restrict__ sc,
    const float* __restrict__ bm_s, const int* __restrict__ bm_i,
    int nblk, int n0,
    float* __restrict__ state_s, int* __restrict__ state_i)
{
    const int q = blockIdx.x;
    const int t = threadIdx.x;
    const int NB = nblk;

    __shared__ float pool_s[NBMAX + 64];
    __shared__ int   pool_i[NBMAX + 64];
    __shared__ float win_s[KK];
    __shared__ int   win_i[KK];

    float* row = sc + (size_t)q * CHUNK;

    if (t < NB) {
        pool_s[t] = bm_s[(size_t)q * nblk + t];
        pool_i[t] = bm_i[(size_t)q * nblk + t];   // chunk-local col
    }
    if (t >= 128 && t - 128 < 64) {               // state entries (global idx)
        pool_s[NB + (t - 128)] = state_s[q * 64 + (t - 128)];
        pool_i[NB + (t - 128)] = state_i[q * 64 + (t - 128)];
    }
    __syncthreads();

    for (int r = 0; r < KK; ++r) {
        float bs = -2e30f; int be = 0;
        if (t < 64) {
            bs = pool_s[t]; be = t;
            for (int e = t + 64; e < NB + 64; e += 64) {
                float v = pool_s[e];
                if (v > bs) { bs = v; be = e; }
            }
            #pragma unroll
            for (int msk = 32; msk; msk >>= 1) {
                float os = __shfl_xor(bs, msk);
                int   oe = __shfl_xor(be, msk);
                if (os > bs || (os == bs && oe < be)) { bs = os; be = oe; }
            }
            if (t == 0) {
                win_s[r] = bs;
                win_i[r] = (be < NB) ? (n0 + pool_i[be]) : pool_i[be];
                if (be < NB) row[pool_i[be]] = -1e30f;   // mark taken
            }
        }
        __syncthreads();   // mark visible before rescan

        if (t < 64) {
            if (be < NB) {
                // rescan winning slice (128 elems, 2 per lane, L1/L2 hits)
                const int base = be * 128;
                float v0 = row[base + t];
                float v1 = row[base + 64 + t];
                int   i0 = base + t;
                int   i1 = base + 64 + t;
                if (v1 > v0) { v0 = v1; i0 = i1; }
                #pragma unroll
                for (int msk = 32; msk; msk >>= 1) {
                    float ov = __shfl_xor(v0, msk);
                    int   oi = __shfl_xor(i0, msk);
                    if (ov > v0) { v0 = ov; i0 = oi; }
                }
                if (t == 0) { pool_s[be] = v0; pool_i[be] = i0; }
            } else if (t == 0) {
                pool_s[be] = -2e30f;    // state entry consumed
            }
        }
        __syncthreads();
    }

    if (t < 64) {
        if (t < KK) {
            state_s[q * 64 + t] = win_s[t];
            state_i[q * 64 + t] = win_i[t];
        } else {
            state_s[q * 64 + t] = -1e30f;
            state_i[q * 64 + t] = 0;
        }
    }
}

// ---------------- vote: class histogram, normalize, write preds + targets ----------------
__global__ __launch_bounds__(256) void knn_vote(
    const float* __restrict__ state_s, const int* __restrict__ state_i,
    const int* __restrict__ labels, const int* __restrict__ targets,
    float* __restrict__ out)
{
    const int q = blockIdx.x;
    const int t = threadIdx.x;
    __shared__ float hist[CC];
    __shared__ float ssum;

    for (int c = t; c < CC; c += 256) hist[c] = 0.f;
    if (t == 0) ssum = 0.f;
    __syncthreads();

    if (t < KK) {
        float s = state_s[q * 64 + t];
        int   idx = state_i[q * 64 + t];
        if (s > -1e29f) {
            int lab = labels[idx];
            atomicAdd(&hist[lab], s);
            atomicAdd(&ssum, s);
        }
    }
    __syncthreads();

    float denom = ssum;
    if (denom == 0.f) denom = 1.f;
    float inv = 1.f / denom;
    for (int c = t; c < CC; c += 256)
        out[(size_t)q * CC + c] = hist[c] * inv;
    if (t == 0)
        out[(size_t)QN * CC + q] = (float)targets[q];
}

// ---------------- host launch ----------------
extern "C" void kernel_launch(void* const* d_in, const int* in_sizes, int n_in,
                              void* d_out, int out_size, void* d_ws, size_t ws_size,
                              hipStream_t stream) {
    const float* samples = (const float*)d_in[0];   // [QN][DD]
    const int*   targets = (const int*)d_in[1];     // [QN]
    const float* train   = (const float*)d_in[2];   // [NN][DD]
    const int*   labels  = (const int*)d_in[3];     // [NN]
    float* out = (float*)d_out;

    char* ws = (char*)d_ws;
    float* state_s = (float*)ws;                               // 512KB
    int*   state_i = (int*)(ws + (512 << 10));                 // 512KB
    short* Ahi = (short*)(ws + (1 << 20));                     // 4MB
    short* Alo = Ahi + (size_t)QN * DD;                        // 4MB
    short* Bhi = (short*)(ws + (16 << 20));                    // ~195.5MB
    short* Blo = Bhi + (size_t)BROWS * DD;                     // ~195.5MB
    size_t bm_off = (size_t)(16 << 20) + 2 * (size_t)BROWS * DD * 2;
    float* bm_s = (float*)(ws + bm_off);                       // QN*98*4 ≈ 0.8MB
    int*   bm_i = (int*)(ws + bm_off + (1 << 20));             // ≈ 0.8MB
    float* scores = (float*)(ws + bm_off + (2 << 20));         // QN*CHUNK*4 ≈ 103MB

    knn_init<<<(QN * 64) / 256, 256, 0, stream>>>(state_s, state_i);
    knn_convert<<<QN,    256, 0, stream>>>(samples, Ahi, Alo, QN);
    knn_convert<<<BROWS, 256, 0, stream>>>(train,   Bhi, Blo, NN);

    for (int n0 = 0; n0 < NN; n0 += CHUNK) {
        int rem        = NN - n0;
        int cols_valid = rem < CHUNK ? rem : CHUNK;
        int cols_pad   = (cols_valid + 127) & ~127;
        int nblk       = cols_pad / 128;
        dim3 grid(QN / 128, nblk);    // q on x (fastest) -> B-tile sharing
        knn_gemm<<<grid, 256, 0, stream>>>(Ahi, Alo, Bhi, Blo, scores, n0, cols_valid);
        int pairs = QN * nblk;
        knn_select<<<(pairs + 3) / 4, 256, 0, stream>>>(scores, bm_s, bm_i, nblk);
        knn_merge<<<QN, 256, 0, stream>>>(scores, bm_s, bm_i, nblk, n0,
                                          state_s, state_i);
    }

    knn_vote<<<QN, 256, 0, stream>>>(state_s, state_i, labels, targets, out);
}

// Round 4
// 2054.034 us; speedup vs baseline: 3.0934x; 1.3667x over previous
//
#include <hip/hip_runtime.h>
#include <hip/hip_bf16.h>

// Problem constants
#define QN    2048
#define NN    100000
#define DD    1024
#define CC    1000
#define KK    50
#define BROWS 100096   // NN padded to multiple of 128
#define NBLK  782      // BROWS / 128

typedef short bf16x8 __attribute__((ext_vector_type(8)));
typedef float f32x4  __attribute__((ext_vector_type(4)));

__device__ __forceinline__ unsigned short f2bf_rn(float x) {
    unsigned u = __float_as_uint(x);
    u += 0x7fff + ((u >> 16) & 1);          // round-to-nearest-even
    return (unsigned short)(u >> 16);
}
__device__ __forceinline__ float bf2f(unsigned short h) {
    return __uint_as_float(((unsigned)h) << 16);
}

// ---------------- convert: fp32 -> bf16 hi + bf16 lo(residual) ----------------
__global__ __launch_bounds__(256) void knn_convert(
    const float* __restrict__ src, short* __restrict__ hi, short* __restrict__ lo,
    int rows_valid)
{
    const int n  = blockIdx.x;
    const int k4 = threadIdx.x << 2;
    float4 v = make_float4(0.f, 0.f, 0.f, 0.f);
    if (n < rows_valid)
        v = *reinterpret_cast<const float4*>(&src[(size_t)n * DD + k4]);

    unsigned short h0 = f2bf_rn(v.x), h1 = f2bf_rn(v.y);
    unsigned short h2 = f2bf_rn(v.z), h3 = f2bf_rn(v.w);
    short4 hv = make_short4((short)h0, (short)h1, (short)h2, (short)h3);
    short4 lv = make_short4((short)f2bf_rn(v.x - bf2f(h0)),
                            (short)f2bf_rn(v.y - bf2f(h1)),
                            (short)f2bf_rn(v.z - bf2f(h2)),
                            (short)f2bf_rn(v.w - bf2f(h3)));
    *reinterpret_cast<short4*>(&hi[(size_t)n * DD + k4]) = hv;
    *reinterpret_cast<short4*>(&lo[(size_t)n * DD + k4]) = lv;
}

// ---------------- MFMA GEMM + fused per-(row,128col-block) argmax ----------------
// 128x128 tile, BK=32, 4 waves (64x64 each via 4x4 of 16x16x32 bf16).
// LDS chunk-XOR swizzle: slot chunk c_slot holds data chunk c_slot ^ ((row>>1)&3)
// so fragment ds_read_b128 spreads over all 32 banks (2-way, free) instead of
// 8-way on banks {0-3,16-19}.
#define GL(gptr, ldsptr) __builtin_amdgcn_global_load_lds(                    \
    (const __attribute__((address_space(1))) void*)(gptr),                    \
    (__attribute__((address_space(3))) void*)(ldsptr), 16, 0, 0)

__global__ __launch_bounds__(256) void knn_gemm(
    const short* __restrict__ Ahi, const short* __restrict__ Alo,
    const short* __restrict__ Bhi, const short* __restrict__ Blo,
    float* __restrict__ out, float* __restrict__ bm_s, int* __restrict__ bm_i)
{
    __shared__ short As_hi[128][32];
    __shared__ short As_lo[128][32];
    __shared__ short Bs_hi[128][32];
    __shared__ short Bs_lo[128][32];
    __shared__ float red_s[2][128];
    __shared__ int   red_i[2][128];

    const int tid  = threadIdx.x;
    const int lane = tid & 63;
    const int w    = tid >> 6;
    const int wm   = (w >> 1) * 64;      // wave's M offset in tile
    const int wn   = (w & 1) * 64;       // wave's N offset in tile
    const int q0   = blockIdx.x * 128;   // q on x: adjacent blocks share B tile
    const int c0   = blockIdx.y * 128;

    const int srow = w * 32 + (lane >> 2);                    // staging row (GL#1), +16 for GL#2
    const int kb   = (((lane & 3) ^ ((lane >> 3) & 3)) * 16); // swizzled chunk byte offset
    const int fr   = lane & 15;              // fragment row (m or n)
    const int fq   = lane >> 4;              // fragment quad (k-chunk)

    f32x4 acc[4][4];
    #pragma unroll
    for (int i = 0; i < 4; ++i)
        #pragma unroll
        for (int j = 0; j < 4; ++j)
            acc[i][j] = (f32x4){0.f, 0.f, 0.f, 0.f};

    const size_t arow = (size_t)(q0 + srow);
    const size_t brow = (size_t)(c0 + srow);
    char* lds_ah = (char*)As_hi + (w * 32) * 64;   // wave-uniform LDS bases
    char* lds_al = (char*)As_lo + (w * 32) * 64;
    char* lds_bh = (char*)Bs_hi + (w * 32) * 64;
    char* lds_bl = (char*)Bs_lo + (w * 32) * 64;

    for (int k0 = 0; k0 < DD; k0 += 32) {
        const size_t ab = (arow * DD + k0) * 2 + kb;     // byte offsets
        const size_t bb = (brow * DD + k0) * 2 + kb;
        const size_t rstep = (size_t)16 * DD * 2;        // +16 rows

        GL((const char*)Ahi + ab,         lds_ah);
        GL((const char*)Ahi + ab + rstep, lds_ah + 16 * 64);
        GL((const char*)Alo + ab,         lds_al);
        GL((const char*)Alo + ab + rstep, lds_al + 16 * 64);
        GL((const char*)Bhi + bb,         lds_bh);
        GL((const char*)Bhi + bb + rstep, lds_bh + 16 * 64);
        GL((const char*)Blo + bb,         lds_bl);
        GL((const char*)Blo + bb + rstep, lds_bl + 16 * 64);
        __syncthreads();   // drains vmcnt(0) before barrier

        bf16x8 ah[4], al[4], bh[4], bl[4];
        #pragma unroll
        for (int i = 0; i < 4; ++i) {
            const int ra = wm + i * 16 + fr;
            const int rb = wn + i * 16 + fr;
            const int ca = (fq ^ ((ra >> 1) & 3)) * 8;   // swizzled read chunk
            const int cb = (fq ^ ((rb >> 1) & 3)) * 8;
            ah[i] = *reinterpret_cast<const bf16x8*>(&As_hi[ra][ca]);
            al[i] = *reinterpret_cast<const bf16x8*>(&As_lo[ra][ca]);
            bh[i] = *reinterpret_cast<const bf16x8*>(&Bs_hi[rb][cb]);
            bl[i] = *reinterpret_cast<const bf16x8*>(&Bs_lo[rb][cb]);
        }

        #pragma unroll
        for (int i = 0; i < 4; ++i)
            #pragma unroll
            for (int j = 0; j < 4; ++j) {
                acc[i][j] = __builtin_amdgcn_mfma_f32_16x16x32_bf16(ah[i], bh[j], acc[i][j], 0, 0, 0);
                acc[i][j] = __builtin_amdgcn_mfma_f32_16x16x32_bf16(al[i], bh[j], acc[i][j], 0, 0, 0);
                acc[i][j] = __builtin_amdgcn_mfma_f32_16x16x32_bf16(ah[i], bl[j], acc[i][j], 0, 0, 0);
            }
        __syncthreads();
    }

    // epilogue: D layout col=lane&15, row=(lane>>4)*4+reg  [m89-verified]
    // write scores (padded cols -> -1e30) + fused per-row max over this block's cols
    #pragma unroll
    for (int i = 0; i < 4; ++i) {
        const int qrow = q0 + wm + i * 16 + fq * 4;
        float rv[4]; int rc[4];
        #pragma unroll
        for (int r = 0; r < 4; ++r) { rv[r] = -3e30f; rc[r] = 0; }
        #pragma unroll
        for (int j = 0; j < 4; ++j) {
            const int col = c0 + wn + j * 16 + fr;
            const bool ok = (col < NN);
            float* dst = &out[(size_t)qrow * BROWS + col];
            #pragma unroll
            for (int r = 0; r < 4; ++r) {
                float v = ok ? acc[i][j][r] : -1e30f;
                dst[r * (size_t)BROWS] = v;
                if (v > rv[r]) { rv[r] = v; rc[r] = col; }   // ascending j: ties keep smaller col
            }
        }
        #pragma unroll
        for (int r = 0; r < 4; ++r) {
            float v = rv[r]; int c = rc[r];
            #pragma unroll
            for (int m = 1; m <= 8; m <<= 1) {               // reduce across fr (16-lane group)
                float ov = __shfl_xor(v, m);
                int   oc = __shfl_xor(c, m);
                if (ov > v || (ov == v && oc < c)) { v = ov; c = oc; }
            }
            if (fr == 0) {
                red_s[w & 1][wm + i * 16 + fq * 4 + r] = v;
                red_i[w & 1][wm + i * 16 + fq * 4 + r] = c;
            }
        }
    }
    __syncthreads();
    if (tid < 128) {
        float v0 = red_s[0][tid], v1 = red_s[1][tid];
        int   i0 = red_i[0][tid], i1 = red_i[1][tid];
        bool take1 = (v1 > v0) || (v1 == v0 && i1 < i0);
        bm_s[(size_t)(q0 + tid) * NBLK + blockIdx.y] = take1 ? v1 : v0;
        bm_i[(size_t)(q0 + tid) * NBLK + blockIdx.y] = take1 ? i1 : i0;
    }
}

// ---------------- merge: per-query top-50 from 782 block maxima ----------------
// one wave per query; 50 rounds of (LDS argmax over 782 + 128-elem slice rescan)
__global__ __launch_bounds__(64) void knn_merge(
    float* __restrict__ sc,
    const float* __restrict__ bm_s, const int* __restrict__ bm_i,
    float* __restrict__ top_s, int* __restrict__ top_i)
{
    const int q = blockIdx.x;
    const int t = threadIdx.x;

    __shared__ float pool_s[NBLK];
    __shared__ int   pool_i[NBLK];
    __shared__ float win_s[KK];
    __shared__ int   win_i[KK];

    float* row = sc + (size_t)q * BROWS;

    for (int e = t; e < NBLK; e += 64) {
        pool_s[e] = bm_s[(size_t)q * NBLK + e];
        pool_i[e] = bm_i[(size_t)q * NBLK + e];
    }
    __syncthreads();

    for (int r = 0; r < KK; ++r) {
        // argmax over pool; pool order == col order, so tie -> smaller e == smaller col
        float bs = -3e30f; int be = 0;
        for (int e = t; e < NBLK; e += 64) {
            float v = pool_s[e];
            if (v > bs) { bs = v; be = e; }
        }
        #pragma unroll
        for (int m = 32; m; m >>= 1) {
            float ov = __shfl_xor(bs, m);
            int   oe = __shfl_xor(be, m);
            if (ov > bs || (ov == bs && oe < be)) { bs = ov; be = oe; }
        }
        if (t == 0) {
            win_s[r] = bs;
            win_i[r] = pool_i[be];
            row[pool_i[be]] = -1e30f;            // mark taken
        }
        __syncthreads();                          // mark visible before rescan

        {   // rescan winning 128-col slice
            const int base = be * 128;
            float v0 = row[base + t], v1 = row[base + 64 + t];
            int   i0 = base + t,      i1 = base + 64 + t;
            if (v1 > v0) { v0 = v1; i0 = i1; }
            #pragma unroll
            for (int m = 32; m; m >>= 1) {
                float ov = __shfl_xor(v0, m);
                int   oi = __shfl_xor(i0, m);
                if (ov > v0 || (ov == v0 && oi < i0)) { v0 = ov; i0 = oi; }
            }
            if (t == 0) { pool_s[be] = v0; pool_i[be] = i0; }
        }
        __syncthreads();
    }

    if (t < KK) { top_s[q * 64 + t] = win_s[t]; top_i[q * 64 + t] = win_i[t]; }
    else        { top_s[q * 64 + t] = -1e30f;   top_i[q * 64 + t] = 0; }
}

// ---------------- vote: class histogram, normalize, write preds + targets ----------------
__global__ __launch_bounds__(256) void knn_vote(
    const float* __restrict__ top_s, const int* __restrict__ top_i,
    const int* __restrict__ labels, const int* __restrict__ targets,
    float* __restrict__ out)
{
    const int q = blockIdx.x;
    const int t = threadIdx.x;
    __shared__ float hist[CC];
    __shared__ float ssum;

    for (int c = t; c < CC; c += 256) hist[c] = 0.f;
    if (t == 0) ssum = 0.f;
    __syncthreads();

    if (t < KK) {
        float s = top_s[q * 64 + t];
        int   idx = top_i[q * 64 + t];
        if (s > -1e29f) {
            int lab = labels[idx];
            atomicAdd(&hist[lab], s);
            atomicAdd(&ssum, s);
        }
    }
    __syncthreads();

    float denom = ssum;
    if (denom == 0.f) denom = 1.f;
    float inv = 1.f / denom;
    for (int c = t; c < CC; c += 256)
        out[(size_t)q * CC + c] = hist[c] * inv;
    if (t == 0)
        out[(size_t)QN * CC + q] = (float)targets[q];
}

// ---------------- host launch ----------------
extern "C" void kernel_launch(void* const* d_in, const int* in_sizes, int n_in,
                              void* d_out, int out_size, void* d_ws, size_t ws_size,
                              hipStream_t stream) {
    const float* samples = (const float*)d_in[0];   // [QN][DD]
    const int*   targets = (const int*)d_in[1];     // [QN]
    const float* train   = (const float*)d_in[2];   // [NN][DD]
    const int*   labels  = (const int*)d_in[3];     // [NN]
    float* out = (float*)d_out;

    char* ws = (char*)d_ws;
    short* Ahi = (short*)ws;                                     // 4MB
    short* Alo = Ahi + (size_t)QN * DD;                          // 4MB
    short* Bhi = (short*)(ws + (16 << 20));                      // 195.5MB
    short* Blo = Bhi + (size_t)BROWS * DD;                       // 195.5MB
    size_t bm_off = (size_t)(16 << 20) + 2 * (size_t)BROWS * DD * 2;
    float* bm_s = (float*)(ws + bm_off);                         // 2048*782*4 ≈ 6.1MB
    int*   bm_i = (int*)(ws + bm_off + (8 << 20));               // ≈ 6.1MB
    float* top_s = (float*)(ws + bm_off + (16 << 20));           // 512KB
    int*   top_i = (int*)(ws + bm_off + (17 << 20));             // 512KB
    float* scores = (float*)(ws + bm_off + (18 << 20));          // 2048*100096*4 ≈ 820MB

    knn_convert<<<QN,    256, 0, stream>>>(samples, Ahi, Alo, QN);
    knn_convert<<<BROWS, 256, 0, stream>>>(train,   Bhi, Blo, NN);

    dim3 grid(QN / 128, NBLK);    // q on x (fastest) -> 16 consecutive blocks share B tile
    knn_gemm<<<grid, 256, 0, stream>>>(Ahi, Alo, Bhi, Blo, scores, bm_s, bm_i);

    knn_merge<<<QN, 64, 0, stream>>>(scores, bm_s, bm_i, top_s, top_i);
    knn_vote<<<QN, 256, 0, stream>>>(top_s, top_i, labels, targets, out);
}